// Round 1
// baseline (1716.042 us; speedup 1.0000x reference)
//
#include <hip/hip_runtime.h>

// Problem constants (AblationDecoder: B=8, N=50000, DIM=3, C_DIM=64, TASK_DIM=512, H=64, NB=5, OUT=12)
#define B_    8
#define N_    50000
#define DIM_  3
#define CDIM_ 64
#define TDIM_ 512
#define H_    64
#define NB_   5
#define OUT_  12
#define TOTAL_ (B_ * N_)

// ---------------------------------------------------------------------------
// Kernel 1: task_proj[b][i][j] = fc_c_b[i][j] + sum_t task_feature[b][t] * fc_c_W[i][64+t][j]
// Tiny (B*NB*H = 2560 outputs, 512-deep dots). One block of 256 per (b,i):
// 4 groups of 64 lanes each take 128 t's, LDS-reduce.
// ---------------------------------------------------------------------------
__global__ void task_proj_kernel(const float* __restrict__ task_feature,
                                 const float* __restrict__ fc_c_W,
                                 const float* __restrict__ fc_c_b,
                                 float* __restrict__ task_proj) {
    __shared__ float partial[4][H_];
    int bi = blockIdx.x;            // 0 .. B*NB-1
    int b = bi / NB_, i = bi % NB_;
    int j = threadIdx.x & 63;
    int g = threadIdx.x >> 6;       // 0..3
    const float* W  = fc_c_W + ((size_t)i * (CDIM_ + TDIM_) + CDIM_) * H_; // rows 64..575
    const float* tf = task_feature + (size_t)b * TDIM_;
    float acc = 0.f;
    int t0 = g * (TDIM_ / 4);
    #pragma unroll 8
    for (int t = 0; t < TDIM_ / 4; ++t) {
        acc += tf[t0 + t] * W[(size_t)(t0 + t) * H_ + j];   // tf uniform -> s_load; W coalesced
    }
    partial[g][j] = acc;
    __syncthreads();
    if (g == 0) {
        float s = partial[0][j] + partial[1][j] + partial[2][j] + partial[3][j]
                + fc_c_b[i * H_ + j];
        task_proj[(b * NB_ + i) * H_ + j] = s;
    }
}

// ---------------------------------------------------------------------------
// Kernel 2: main decoder. One thread per point; net[64] & h[64] live in VGPRs
// (all loops indexing them are fully unrolled). Weight accesses are wave-
// uniform -> expect s_load + SGPR-operand v_fmac.
// ---------------------------------------------------------------------------
__global__ __launch_bounds__(256) void decoder_kernel(
    const float* __restrict__ p, const float* __restrict__ c,
    const float* __restrict__ fc_p_W, const float* __restrict__ fc_p_b,
    const float* __restrict__ fc_c_W,
    const float* __restrict__ blk0_W, const float* __restrict__ blk0_b,
    const float* __restrict__ blk1_W, const float* __restrict__ blk1_b,
    const float* __restrict__ fc_out_W, const float* __restrict__ fc_out_b,
    const float* __restrict__ task_proj,
    float* __restrict__ out) {
    int idx = blockIdx.x * 256 + threadIdx.x;
    if (idx >= TOTAL_) return;
    int b = idx / N_;

    float net[H_];
    {
        float p0 = p[(size_t)idx * 3 + 0];
        float p1 = p[(size_t)idx * 3 + 1];
        float p2 = p[(size_t)idx * 3 + 2];
        #pragma unroll
        for (int j = 0; j < H_; ++j) {
            net[j] = fc_p_b[j] + p0 * fc_p_W[j] + p1 * fc_p_W[H_ + j] + p2 * fc_p_W[2 * H_ + j];
        }
    }
    const float* crow = c + (size_t)idx * CDIM_;   // 256B-aligned -> float4 ok

    #pragma unroll 1   // keep the 5-block body from exploding I-cache further
    for (int i = 0; i < NB_; ++i) {
        // --- conditioning: net += c @ Wc + task_proj (task part precomputed, incl. fc_c_b)
        const float* Wc = fc_c_W + (size_t)i * (CDIM_ + TDIM_) * H_;
        const float* tp = task_proj + (b * NB_ + i) * H_;
        #pragma unroll
        for (int j = 0; j < H_; ++j) net[j] += tp[j];
        #pragma unroll 4
        for (int k = 0; k < CDIM_; k += 4) {
            float4 c4 = *reinterpret_cast<const float4*>(crow + k);
            const float* w0 = Wc + (size_t)k * H_;
            const float* w1 = w0 + H_;
            const float* w2 = w0 + 2 * H_;
            const float* w3 = w0 + 3 * H_;
            #pragma unroll
            for (int j = 0; j < H_; ++j) {
                net[j] += c4.x * w0[j] + c4.y * w1[j] + c4.z * w2[j] + c4.w * w3[j];
            }
        }
        // --- ResnetBlockFC: h = relu(net) @ W0 + b0
        float h[H_];
        const float* W0 = blk0_W + (size_t)i * H_ * H_;
        const float* b0 = blk0_b + i * H_;
        #pragma unroll
        for (int j = 0; j < H_; ++j) h[j] = b0[j];
        #pragma unroll
        for (int k = 0; k < H_; ++k) {          // full unroll: net[k] must be reg-indexed
            float xk = fmaxf(net[k], 0.f);
            const float* wr = W0 + k * H_;
            #pragma unroll
            for (int j = 0; j < H_; ++j) h[j] += xk * wr[j];
        }
        // --- net += relu(h) @ W1 + b1
        const float* W1 = blk1_W + (size_t)i * H_ * H_;
        const float* b1 = blk1_b + i * H_;
        #pragma unroll
        for (int j = 0; j < H_; ++j) net[j] += b1[j];
        #pragma unroll
        for (int k = 0; k < H_; ++k) {
            float hk = fmaxf(h[k], 0.f);
            const float* wr = W1 + k * H_;
            #pragma unroll
            for (int j = 0; j < H_; ++j) net[j] += hk * wr[j];
        }
    }
    // --- out = relu(net) @ fc_out_W + fc_out_b
    float o[OUT_];
    #pragma unroll
    for (int q = 0; q < OUT_; ++q) o[q] = fc_out_b[q];
    #pragma unroll
    for (int k = 0; k < H_; ++k) {
        float xk = fmaxf(net[k], 0.f);
        #pragma unroll
        for (int q = 0; q < OUT_; ++q) o[q] += xk * fc_out_W[k * OUT_ + q];
    }
    #pragma unroll
    for (int q = 0; q < OUT_; ++q) out[(size_t)idx * OUT_ + q] = o[q];
}

// ---------------------------------------------------------------------------
extern "C" void kernel_launch(void* const* d_in, const int* in_sizes, int n_in,
                              void* d_out, int out_size, void* d_ws, size_t ws_size,
                              hipStream_t stream) {
    const float* p        = (const float*)d_in[0];
    const float* c        = (const float*)d_in[1];
    const float* tf       = (const float*)d_in[2];
    const float* fc_p_W   = (const float*)d_in[3];
    const float* fc_p_b   = (const float*)d_in[4];
    const float* fc_c_W   = (const float*)d_in[5];
    const float* fc_c_b   = (const float*)d_in[6];
    const float* blk0_W   = (const float*)d_in[7];
    const float* blk0_b   = (const float*)d_in[8];
    const float* blk1_W   = (const float*)d_in[9];
    const float* blk1_b   = (const float*)d_in[10];
    const float* fc_out_W = (const float*)d_in[11];
    const float* fc_out_b = (const float*)d_in[12];
    float* out = (float*)d_out;
    float* task_proj = (float*)d_ws;   // needs B*NB*H*4 = 10240 B of workspace

    task_proj_kernel<<<B_ * NB_, 256, 0, stream>>>(tf, fc_c_W, fc_c_b, task_proj);
    decoder_kernel<<<(TOTAL_ + 255) / 256, 256, 0, stream>>>(
        p, c, fc_p_W, fc_p_b, fc_c_W, blk0_W, blk0_b, blk1_W, blk1_b,
        fc_out_W, fc_out_b, task_proj, out);
}

// Round 2
// 340.306 us; speedup vs baseline: 5.0426x; 5.0426x over previous
//
#include <hip/hip_runtime.h>

// AblationDecoder: B=8, N=50000, DIM=3, C_DIM=64, TASK_DIM=512, H=64, NB=5, OUT=12
#define B_    8
#define N_    50000
#define H_    64
#define NB_   5
#define OUT_  12

#define PTS_PER_BLOCK   448
#define TILES_PER_WAVE  7
#define BLOCKS_PER_BATCH 112   // ceil(50000/448); 50000 % 16 == 0 so tail is whole tiles
#define THREADS 256

// LDS layout (bytes). Row stride = 72 halves (144 B) -> 16B-aligned rows, phase-uniform banks for b128.
#define C_OFF    0         // c_lds   [448][72] f16 = 64512 B
#define ACT_OFF  64512     // act     [448][72] f16 = 64512 B
#define W_OFF    129024    // w_lds [3][64][72] f16 = 27648 B
#define FCO_OFF  156672    // fc_out A [16][72] f16 = 2304 B
#define FPW_OFF  158976    // fc_p_W  [3][64] f32  = 768 B
#define B0_OFF   159744    // blk0_b  [64] f32     = 256 B
#define B1_OFF   160000    // blk1_b  [64] f32     = 256 B
#define TP_OFF   160256    // tp      [5][64] f16  = 640 B
#define FOB_OFF  160896    // fc_out_b[12] f32     = 48 B
#define SMEM_BYTES 160944

typedef _Float16 half8 __attribute__((ext_vector_type(8)));
typedef float   floatx4 __attribute__((ext_vector_type(4)));

// k-permutation: swap bits[5:4] <-> bits[3:2]; self-inverse. Makes a lane's packed D
// dwords land contiguous in LDS. Applied to BOTH weights and activations -> dot invariant.
__device__ __host__ __forceinline__ int sigma_k(int k) {
    return ((k & 0x30) >> 2) | ((k & 0x0C) << 2) | (k & 3);
}

__device__ __forceinline__ unsigned pack2(float a, float b) {
    union { _Float16 h[2]; unsigned u; } x;
    x.h[0] = (_Float16)a; x.h[1] = (_Float16)b;
    return x.u;
}
__device__ __forceinline__ half8 ldh8(const _Float16* p) {
    union { uint4 u; half8 h; } x;
    x.u = *(const uint4*)p;
    return x.h;
}

// relu + f16-pack a lane's 16 D-layout values (4 f-tiles x 4 regs) and store as 2x b128.
// dst = act_row + 16*q halves (dword base 8q); dword (T,p) -> offset 2T+p  (k' = sigma(f)).
__device__ __forceinline__ void store_act_row(_Float16* dst, const floatx4* v) {
    uint4 w0, w1;
    w0.x = pack2(fmaxf(v[0][0], 0.f), fmaxf(v[0][1], 0.f));
    w0.y = pack2(fmaxf(v[0][2], 0.f), fmaxf(v[0][3], 0.f));
    w0.z = pack2(fmaxf(v[1][0], 0.f), fmaxf(v[1][1], 0.f));
    w0.w = pack2(fmaxf(v[1][2], 0.f), fmaxf(v[1][3], 0.f));
    w1.x = pack2(fmaxf(v[2][0], 0.f), fmaxf(v[2][1], 0.f));
    w1.y = pack2(fmaxf(v[2][2], 0.f), fmaxf(v[2][3], 0.f));
    w1.z = pack2(fmaxf(v[3][0], 0.f), fmaxf(v[3][1], 0.f));
    w1.w = pack2(fmaxf(v[3][2], 0.f), fmaxf(v[3][3], 0.f));
    *(uint4*)(dst)     = w0;
    *(uint4*)(dst + 8) = w1;
}

// ---------------------------------------------------------------------------
// Pre-kernel 1: tp[b][i][j] = fc_c_b[i][j] + sum_t tf[b][t]*fc_c_W[i][64+t][j]
//               (+ fc_p_b[j] folded into i==0).  f16 out.
// ---------------------------------------------------------------------------
__global__ void task_proj_kernel(const float* __restrict__ tf,
                                 const float* __restrict__ fc_c_W,
                                 const float* __restrict__ fc_c_b,
                                 const float* __restrict__ fc_p_b,
                                 _Float16* __restrict__ tp_out) {
    __shared__ float partial[4][64];
    int bi = blockIdx.x;            // 0..39
    int b = bi / NB_, i = bi % NB_;
    int j = threadIdx.x & 63;
    int g = threadIdx.x >> 6;
    const float* W  = fc_c_W + ((size_t)i * 576 + 64) * 64;
    const float* tb = tf + b * 512;
    float acc = 0.f;
    int t0 = g * 128;
    #pragma unroll 8
    for (int t = 0; t < 128; ++t)
        acc += tb[t0 + t] * W[(size_t)(t0 + t) * 64 + j];
    partial[g][j] = acc;
    __syncthreads();
    if (g == 0) {
        float s = partial[0][j] + partial[1][j] + partial[2][j] + partial[3][j]
                + fc_c_b[i * 64 + j];
        if (i == 0) s += fc_p_b[j];
        tp_out[(b * NB_ + i) * 64 + j] = (_Float16)s;
    }
}

// ---------------------------------------------------------------------------
// Pre-kernel 2: build f16, transposed, sigma-permuted weights in ws:
//   ws_w[(mat*5+i)*4096 + n*64 + sigma(k)] = W[i][k][n]   (mat: 0=Wc(c-part),1=blk0,2=blk1)
//   ws_fco[m*64 + sigma(k)] = fc_out_W[k][m] (m<12 else 0)
// ---------------------------------------------------------------------------
__global__ void prep_weights(const float* __restrict__ fc_c_W,
                             const float* __restrict__ blk0_W,
                             const float* __restrict__ blk1_W,
                             const float* __restrict__ fc_out_W,
                             _Float16* __restrict__ ws_w,
                             _Float16* __restrict__ ws_fco) {
    int idx = blockIdx.x * THREADS + threadIdx.x;
    if (idx < 61440) {
        int mat = idx / 20480, rem = idx % 20480;
        int i = rem >> 12, rem2 = rem & 4095;
        int n = rem2 >> 6, k = rem2 & 63;
        float v;
        if (mat == 0)      v = fc_c_W[((size_t)i * 576 + k) * 64 + n];
        else if (mat == 1) v = blk0_W[((size_t)i * 64 + k) * 64 + n];
        else               v = blk1_W[((size_t)i * 64 + k) * 64 + n];
        ws_w[((mat * 5 + i) << 12) + (n << 6) + sigma_k(k)] = (_Float16)v;
    } else if (idx < 62464) {
        int e = idx - 61440;
        int m = e >> 6, k = e & 63;
        ws_fco[(m << 6) + sigma_k(k)] =
            (m < OUT_) ? (_Float16)fc_out_W[k * OUT_ + m] : (_Float16)0.f;
    }
}

// ---------------------------------------------------------------------------
// Main fused decoder. 256 threads = 4 waves; wave owns 7 x 16-pt tiles.
// mfma_f32_16x16x32_f16: A = weights [outfeat][k], B = act [pt][k], D[outfeat][pt].
// net (fp32 residual) lives in D-layout regs as the mfma C operand.
// ---------------------------------------------------------------------------
__global__ __launch_bounds__(THREADS, 1) void decoder_kernel(
    const float* __restrict__ p_g, const float* __restrict__ c_g,
    const float* __restrict__ blk0_b, const float* __restrict__ blk1_b,
    const float* __restrict__ fc_p_W, const float* __restrict__ fc_out_b,
    const _Float16* __restrict__ ws_w, const _Float16* __restrict__ ws_fco,
    const _Float16* __restrict__ ws_tp, float* __restrict__ out_g)
{
    extern __shared__ char smem[];
    _Float16* c_lds = (_Float16*)(smem + C_OFF);
    _Float16* act_l = (_Float16*)(smem + ACT_OFF);
    _Float16* w_lds = (_Float16*)(smem + W_OFF);
    _Float16* fco_l = (_Float16*)(smem + FCO_OFF);
    float*    fpw_l = (float*)(smem + FPW_OFF);
    float*    b0_l  = (float*)(smem + B0_OFF);
    float*    b1_l  = (float*)(smem + B1_OFF);
    _Float16* tp_l  = (_Float16*)(smem + TP_OFF);
    float*    fob_l = (float*)(smem + FOB_OFF);

    const int tid   = threadIdx.x;
    const int batch = blockIdx.x / BLOCKS_PER_BATCH;
    const int blk   = blockIdx.x % BLOCKS_PER_BATCH;
    const int base  = blk * PTS_PER_BLOCK;
    const int npts  = min(PTS_PER_BLOCK, N_ - base);
    const int ntiles = npts >> 4;
    const long gbase = (long)batch * N_ + base;

    // ---- stage c (f32 global -> f16 sigma-permuted LDS rows) ----
    for (int u = tid; u < (ntiles << 8); u += THREADS) {
        int pt = u >> 4, k4 = (u & 15) << 2;
        float4 v = *(const float4*)(c_g + (((size_t)(gbase + pt)) << 6) + k4);
        uint2 d;
        d.x = pack2(v.x, v.y);
        d.y = pack2(v.z, v.w);
        *(uint2*)(c_lds + pt * 72 + sigma_k(k4)) = d;  // sigma(k4)%4==0 -> 8B aligned
    }
    // ---- stage fc_out A-matrix [16][72] ----
    for (int u = tid; u < 128; u += THREADS) {
        int m = u >> 3, cw = u & 7;
        *(uint4*)(fco_l + m * 72 + (cw << 3)) = *(const uint4*)(ws_fco + (m << 6) + (cw << 3));
    }
    if (tid < 192) fpw_l[tid] = fc_p_W[tid];
    if (tid < 160) ((unsigned*)tp_l)[tid] = ((const unsigned*)(ws_tp + batch * (NB_ * 64)))[tid];
    if (tid < OUT_) fob_l[tid] = fc_out_b[tid];
    __syncthreads();

    const int lane = tid & 63;
    const int wv   = tid >> 6;
    const int q    = lane >> 4;    // mfma quad: D row group / k-octet
    const int m15  = lane & 15;    // D col (pt) / A row (feat)
    const int t0   = wv * TILES_PER_WAVE;
    int tc = ntiles - t0;
    tc = tc < 0 ? 0 : (tc > TILES_PER_WAVE ? TILES_PER_WAVE : tc);

    // ---- net init: p @ fc_p_W  (bias folded into tp[0]) ----
    floatx4 net4[TILES_PER_WAVE][4];
    #pragma unroll
    for (int t = 0; t < TILES_PER_WAVE; ++t) {
        if (t >= tc) break;
        long g = gbase + ((t0 + t) << 4) + m15;
        float pp0 = p_g[g * 3 + 0], pp1 = p_g[g * 3 + 1], pp2 = p_g[g * 3 + 2];
        #pragma unroll
        for (int T = 0; T < 4; ++T) {
            floatx4 a;
            #pragma unroll
            for (int r = 0; r < 4; ++r) {
                int f = (T << 4) + (q << 2) + r;
                a[r] = pp0 * fpw_l[f] + pp1 * fpw_l[64 + f] + pp2 * fpw_l[128 + f];
            }
            net4[t][T] = a;
        }
    }

    // ---- resblock loop ----
    #pragma unroll 1
    for (int i = 0; i < NB_; ++i) {
        __syncthreads();
        // stage this block's 3 weight mats (f16, already transposed+sigma'd) into padded LDS
        for (int u = tid; u < 1536; u += THREADS) {
            int mat = u >> 9, rem = u & 511, n = rem >> 3, cw = rem & 7;
            *(uint4*)(w_lds + mat * 4608 + n * 72 + (cw << 3)) =
                *(const uint4*)(ws_w + ((mat * 5 + i) << 12) + (n << 6) + (cw << 3));
        }
        if (tid < 64)       b0_l[tid]      = blk0_b[i * 64 + tid];
        else if (tid < 128) b1_l[tid - 64] = blk1_b[i * 64 + tid - 64];
        __syncthreads();

        float tpv[16], bb0[16], bb1[16];
        #pragma unroll
        for (int T = 0; T < 4; ++T)
            #pragma unroll
            for (int r = 0; r < 4; ++r) {
                int f = (T << 4) + (q << 2) + r;
                tpv[T * 4 + r] = (float)tp_l[i * 64 + f];
                bb0[T * 4 + r] = b0_l[f];
                bb1[T * 4 + r] = b1_l[f];
            }

        half8 Af[4][2];
        // ---- conditioning: net += c @ Wc + tp ; write relu(net) to act ----
        #pragma unroll
        for (int T = 0; T < 4; ++T) {
            const _Float16* wr = w_lds + ((T << 4) + m15) * 72;
            Af[T][0] = ldh8(wr + (q << 3));
            Af[T][1] = ldh8(wr + 32 + (q << 3));
        }
        #pragma unroll
        for (int t = 0; t < TILES_PER_WAVE; ++t) {
            if (t >= tc) break;
            int row = ((t0 + t) << 4) + m15;
            const _Float16* cr = c_lds + row * 72;
            half8 B0 = ldh8(cr + (q << 3));
            half8 B1 = ldh8(cr + 32 + (q << 3));
            #pragma unroll
            for (int T = 0; T < 4; ++T) {
                floatx4 a = net4[t][T];
                a = __builtin_amdgcn_mfma_f32_16x16x32_f16(Af[T][0], B0, a, 0, 0, 0);
                a = __builtin_amdgcn_mfma_f32_16x16x32_f16(Af[T][1], B1, a, 0, 0, 0);
                #pragma unroll
                for (int r = 0; r < 4; ++r) a[r] += tpv[T * 4 + r];
                net4[t][T] = a;
            }
            store_act_row(act_l + row * 72 + (q << 4), &net4[t][0]);
        }
        // ---- blk0: h = relu(net) @ W0 + b0 ; write relu(h) over act ----
        #pragma unroll
        for (int T = 0; T < 4; ++T) {
            const _Float16* wr = w_lds + 4608 + ((T << 4) + m15) * 72;
            Af[T][0] = ldh8(wr + (q << 3));
            Af[T][1] = ldh8(wr + 32 + (q << 3));
        }
        #pragma unroll
        for (int t = 0; t < TILES_PER_WAVE; ++t) {
            if (t >= tc) break;
            int row = ((t0 + t) << 4) + m15;
            const _Float16* ar = act_l + row * 72;
            half8 B0 = ldh8(ar + (q << 3));
            half8 B1 = ldh8(ar + 32 + (q << 3));
            floatx4 hh[4];
            #pragma unroll
            for (int T = 0; T < 4; ++T) {
                floatx4 a = { bb0[T * 4 + 0], bb0[T * 4 + 1], bb0[T * 4 + 2], bb0[T * 4 + 3] };
                a = __builtin_amdgcn_mfma_f32_16x16x32_f16(Af[T][0], B0, a, 0, 0, 0);
                a = __builtin_amdgcn_mfma_f32_16x16x32_f16(Af[T][1], B1, a, 0, 0, 0);
                hh[T] = a;
            }
            store_act_row(act_l + row * 72 + (q << 4), hh);
        }
        // ---- blk1: net += relu(h) @ W1 + b1 ----
        #pragma unroll
        for (int T = 0; T < 4; ++T) {
            const _Float16* wr = w_lds + 9216 + ((T << 4) + m15) * 72;
            Af[T][0] = ldh8(wr + (q << 3));
            Af[T][1] = ldh8(wr + 32 + (q << 3));
        }
        #pragma unroll
        for (int t = 0; t < TILES_PER_WAVE; ++t) {
            if (t >= tc) break;
            int row = ((t0 + t) << 4) + m15;
            const _Float16* ar = act_l + row * 72;
            half8 B0 = ldh8(ar + (q << 3));
            half8 B1 = ldh8(ar + 32 + (q << 3));
            #pragma unroll
            for (int T = 0; T < 4; ++T) {
                floatx4 a = { bb1[T * 4 + 0], bb1[T * 4 + 1], bb1[T * 4 + 2], bb1[T * 4 + 3] };
                a = __builtin_amdgcn_mfma_f32_16x16x32_f16(Af[T][0], B0, a, 0, 0, 0);
                a = __builtin_amdgcn_mfma_f32_16x16x32_f16(Af[T][1], B1, a, 0, 0, 0);
                net4[t][T] += a;
            }
        }
    }

    // ---- output: out = relu(net) @ fc_out + b ----
    #pragma unroll
    for (int t = 0; t < TILES_PER_WAVE; ++t) {
        if (t >= tc) break;
        int row = ((t0 + t) << 4) + m15;
        store_act_row(act_l + row * 72 + (q << 4), &net4[t][0]);
    }
    half8 Ao0 = ldh8(fco_l + m15 * 72 + (q << 3));
    half8 Ao1 = ldh8(fco_l + m15 * 72 + 32 + (q << 3));
    float ob[4];
    #pragma unroll
    for (int r = 0; r < 4; ++r) {
        int v = (q << 2) + r;
        ob[r] = (v < OUT_) ? fob_l[v] : 0.f;
    }
    #pragma unroll
    for (int t = 0; t < TILES_PER_WAVE; ++t) {
        if (t >= tc) break;
        int row = ((t0 + t) << 4) + m15;
        const _Float16* ar = act_l + row * 72;
        half8 B0 = ldh8(ar + (q << 3));
        half8 B1 = ldh8(ar + 32 + (q << 3));
        floatx4 a = { ob[0], ob[1], ob[2], ob[3] };
        a = __builtin_amdgcn_mfma_f32_16x16x32_f16(Ao0, B0, a, 0, 0, 0);
        a = __builtin_amdgcn_mfma_f32_16x16x32_f16(Ao1, B1, a, 0, 0, 0);
        if (q < 3) {   // rows 12..15 are padding
            long g = gbase + ((t0 + t) << 4) + m15;
            float4 o4 = make_float4(a[0], a[1], a[2], a[3]);
            *(float4*)(out_g + g * OUT_ + (q << 2)) = o4;
        }
    }
}

// ---------------------------------------------------------------------------
extern "C" void kernel_launch(void* const* d_in, const int* in_sizes, int n_in,
                              void* d_out, int out_size, void* d_ws, size_t ws_size,
                              hipStream_t stream) {
    const float* p        = (const float*)d_in[0];
    const float* c        = (const float*)d_in[1];
    const float* tf       = (const float*)d_in[2];
    const float* fc_p_W   = (const float*)d_in[3];
    const float* fc_p_b   = (const float*)d_in[4];
    const float* fc_c_W   = (const float*)d_in[5];
    const float* fc_c_b   = (const float*)d_in[6];
    const float* blk0_W   = (const float*)d_in[7];
    const float* blk0_b   = (const float*)d_in[8];
    const float* blk1_W   = (const float*)d_in[9];
    const float* blk1_b   = (const float*)d_in[10];
    const float* fc_out_W = (const float*)d_in[11];
    const float* fc_out_b = (const float*)d_in[12];
    float* out = (float*)d_out;

    // d_ws (halves): ws_w [3][5][4096] | ws_fco [16][64] | ws_tp [8][5][64]  = 130048 B total
    _Float16* wsh    = (_Float16*)d_ws;
    _Float16* ws_w   = wsh;
    _Float16* ws_fco = wsh + 61440;
    _Float16* ws_tp  = wsh + 62464;

    prep_weights<<<244, THREADS, 0, stream>>>(fc_c_W, blk0_W, blk1_W, fc_out_W, ws_w, ws_fco);
    task_proj_kernel<<<B_ * NB_, THREADS, 0, stream>>>(tf, fc_c_W, fc_c_b, fc_p_b, ws_tp);

    hipFuncSetAttribute((const void*)decoder_kernel,
                        hipFuncAttributeMaxDynamicSharedMemorySize, SMEM_BYTES);
    decoder_kernel<<<B_ * BLOCKS_PER_BATCH, THREADS, SMEM_BYTES, stream>>>(
        p, c, blk0_b, blk1_b, fc_p_W, fc_out_b, ws_w, ws_fco, ws_tp, out);
}

// Round 3
// 247.697 us; speedup vs baseline: 6.9280x; 1.3739x over previous
//
#include <hip/hip_runtime.h>

// AblationDecoder: B=8, N=50000, DIM=3, C_DIM=64, TASK_DIM=512, H=64, NB=5, OUT=12
// R3 design: register-resident activation chain. MFMA D-layout is re-used as the
// next layer's B-operand via a k-permutation baked into the weights:
//   consumer A slot (h,q,j) holds weight for input feature
//   f_held = 32h + 16*(j>>2) + 4q + (j&3)
// so packB(net4[2h], net4[2h+1]) (relu+cvt, pure registers) is a valid B frag.
// No act LDS, no barriers in the resblock loop, c held in registers for all 5 blocks.
#define B_    8
#define N_    50000
#define NB_   5
#define OUT_  12
#define THREADS 256
#define TILES_ 4                 // 16-pt tiles per wave
#define PTS_PER_BLOCK (TILES_ * 16 * 4)   // 256
#define BLOCKS_PER_BATCH ((N_ + PTS_PER_BLOCK - 1) / PTS_PER_BLOCK)  // 196

typedef _Float16 half8 __attribute__((ext_vector_type(8)));
typedef float   floatx4 __attribute__((ext_vector_type(4)));

__device__ __forceinline__ half8 ldg8(const _Float16* p) {
    union { uint4 u; half8 h; } x;
    x.u = *(const uint4*)p;
    return x.h;
}

// B fragment from two D-layout accumulators (relu + f32->f16), all in registers.
__device__ __forceinline__ half8 packB(floatx4 a, floatx4 b) {
    half8 r;
    r[0] = (_Float16)fmaxf(a[0], 0.f); r[1] = (_Float16)fmaxf(a[1], 0.f);
    r[2] = (_Float16)fmaxf(a[2], 0.f); r[3] = (_Float16)fmaxf(a[3], 0.f);
    r[4] = (_Float16)fmaxf(b[0], 0.f); r[5] = (_Float16)fmaxf(b[1], 0.f);
    r[6] = (_Float16)fmaxf(b[2], 0.f); r[7] = (_Float16)fmaxf(b[3], 0.f);
    return r;
}

// ---------------------------------------------------------------------------
// Pre-kernel 1: tp[b][i][j] = fc_c_b[i][j] + sum_t tf[b][t]*fc_c_W[i][64+t][j]
//               (+ fc_p_b folded into i==0).  f32 out.
// ---------------------------------------------------------------------------
__global__ void task_proj_kernel(const float* __restrict__ tf,
                                 const float* __restrict__ fc_c_W,
                                 const float* __restrict__ fc_c_b,
                                 const float* __restrict__ fc_p_b,
                                 float* __restrict__ tp_out) {
    __shared__ float partial[4][64];
    int bi = blockIdx.x;            // 0..39
    int b = bi / NB_, i = bi % NB_;
    int j = threadIdx.x & 63;
    int g = threadIdx.x >> 6;
    const float* W  = fc_c_W + ((size_t)i * 576 + 64) * 64;
    const float* tb = tf + b * 512;
    float acc = 0.f;
    int t0 = g * 128;
    #pragma unroll 8
    for (int t = 0; t < 128; ++t)
        acc += tb[t0 + t] * W[(size_t)(t0 + t) * 64 + j];
    partial[g][j] = acc;
    __syncthreads();
    if (g == 0) {
        float s = partial[0][j] + partial[1][j] + partial[2][j] + partial[3][j]
                + fc_c_b[i * 64 + j];
        if (i == 0) s += fc_p_b[j];
        tp_out[(b * NB_ + i) * 64 + j] = s;
    }
}

// ---------------------------------------------------------------------------
// Pre-kernel 2: build f16 A-fragment-ordered weights in ws.
// ws_w chunk index (16B units): ((mat*5+i)*4 + T)*128 + h*64 + q*16 + m15
//   chunk halves j=0..7:
//     mat==0 (Wc, consumes natural-k c):   feature k = 32h + 8q + j
//     mat==1/2 (blk0/blk1, register path): feature f = 32h + 16*(j>>2) + 4q + (j&3)
//   value = W[i][feature][n = T*16 + m15]
// ws_fco chunk index: h*64 + q*16 + m15; sigma'd k; n = m15 (<12 else 0)
// ---------------------------------------------------------------------------
__global__ void prep_weights(const float* __restrict__ fc_c_W,
                             const float* __restrict__ blk0_W,
                             const float* __restrict__ blk1_W,
                             const float* __restrict__ fc_out_W,
                             _Float16* __restrict__ ws_w,
                             _Float16* __restrict__ ws_fco) {
    int u = blockIdx.x * THREADS + threadIdx.x;
    if (u < 7680) {
        int m15 = u & 15, q = (u >> 4) & 3, h = (u >> 6) & 1, T = (u >> 7) & 3;
        int mi = u >> 9;               // 0..14
        int mat = mi / 5, i = mi % 5;
        int n = T * 16 + m15;
        _Float16 out[8];
        #pragma unroll
        for (int j = 0; j < 8; ++j) {
            float v;
            if (mat == 0) {
                int k = 32 * h + 8 * q + j;
                v = fc_c_W[((size_t)i * 576 + k) * 64 + n];
            } else {
                int f = 32 * h + 16 * (j >> 2) + 4 * q + (j & 3);
                const float* W = (mat == 1) ? blk0_W : blk1_W;
                v = W[((size_t)i * 64 + f) * 64 + n];
            }
            out[j] = (_Float16)v;
        }
        *(uint4*)(ws_w + (size_t)u * 8) = *(uint4*)out;
    } else if (u < 7808) {
        int e = u - 7680;
        int m15 = e & 15, q = (e >> 4) & 3, h = (e >> 6) & 1;
        _Float16 out[8];
        #pragma unroll
        for (int j = 0; j < 8; ++j) {
            int f = 32 * h + 16 * (j >> 2) + 4 * q + (j & 3);
            out[j] = (m15 < OUT_) ? (_Float16)fc_out_W[f * OUT_ + m15] : (_Float16)0.f;
        }
        *(uint4*)(ws_fco + (size_t)e * 8) = *(uint4*)out;
    }
}

// ---------------------------------------------------------------------------
// Main decoder: 4 waves x 4 tiles of 16 pts. Everything register-resident.
// ---------------------------------------------------------------------------
__global__ __launch_bounds__(THREADS, 2) void decoder_kernel(
    const float* __restrict__ p_g, const float* __restrict__ c_g,
    const float* __restrict__ blk0_b, const float* __restrict__ blk1_b,
    const float* __restrict__ fc_p_W, const float* __restrict__ fc_out_b,
    const _Float16* __restrict__ ws_w, const _Float16* __restrict__ ws_fco,
    const float* __restrict__ ws_tp, float* __restrict__ out_g)
{
    __shared__ float fpw_l[192];
    __shared__ float b0_l[NB_ * 64];
    __shared__ float b1_l[NB_ * 64];
    __shared__ float tp_l[NB_ * 64];
    __shared__ float fob_l[16];

    const int tid   = threadIdx.x;
    const int batch = blockIdx.x / BLOCKS_PER_BATCH;
    const int blk   = blockIdx.x % BLOCKS_PER_BATCH;
    const int base  = blk * PTS_PER_BLOCK;
    const int npts  = min(PTS_PER_BLOCK, N_ - base);
    const int ntiles = npts >> 4;          // N_ % 16 == 0 -> whole tiles
    const long gbase = (long)batch * N_ + base;

    if (tid < 192) fpw_l[tid] = fc_p_W[tid];
    for (int u = tid; u < NB_ * 64; u += THREADS) {
        b0_l[u] = blk0_b[u];
        b1_l[u] = blk1_b[u];
        tp_l[u] = ws_tp[batch * (NB_ * 64) + u];
    }
    if (tid < 16) fob_l[tid] = (tid < OUT_) ? fc_out_b[tid] : 0.f;
    __syncthreads();

    const int lane = tid & 63;
    const int wv   = tid >> 6;
    const int q    = lane >> 4;
    const int m15  = lane & 15;

    // tiles owned by this wave: tile = wv + 4t (interleaved for tail balance)
    int tileid[TILES_];
    bool act[TILES_];
    #pragma unroll
    for (int t = 0; t < TILES_; ++t) {
        tileid[t] = wv + 4 * t;
        act[t] = (tileid[t] < ntiles);
    }

    // ---- c -> B-operand registers, held for the whole kernel ----
    // cB[t][h] elem j = (f16) c[pt][32h + 8q + j]
    half8 cB[TILES_][2];
    #pragma unroll
    for (int t = 0; t < TILES_; ++t) {
        if (!act[t]) continue;
        const float* cr = c_g + (size_t)(gbase + tileid[t] * 16 + m15) * 64;
        #pragma unroll
        for (int h = 0; h < 2; ++h) {
            float4 v0 = *(const float4*)(cr + 32 * h + 8 * q);
            float4 v1 = *(const float4*)(cr + 32 * h + 8 * q + 4);
            half8 r;
            r[0] = (_Float16)v0.x; r[1] = (_Float16)v0.y;
            r[2] = (_Float16)v0.z; r[3] = (_Float16)v0.w;
            r[4] = (_Float16)v1.x; r[5] = (_Float16)v1.y;
            r[6] = (_Float16)v1.z; r[7] = (_Float16)v1.w;
            cB[t][h] = r;
        }
    }

    // ---- net init: p @ fc_p_W (biases folded into tp[0]) ----
    floatx4 net4[TILES_][4];
    #pragma unroll
    for (int t = 0; t < TILES_; ++t) {
        if (!act[t]) continue;
        long g = gbase + tileid[t] * 16 + m15;
        float pp0 = p_g[g * 3 + 0], pp1 = p_g[g * 3 + 1], pp2 = p_g[g * 3 + 2];
        #pragma unroll
        for (int T = 0; T < 4; ++T) {
            #pragma unroll
            for (int r = 0; r < 4; ++r) {
                int f = (T << 4) + (q << 2) + r;
                net4[t][T][r] = pp0 * fpw_l[f] + pp1 * fpw_l[64 + f] + pp2 * fpw_l[128 + f];
            }
        }
    }

    // ---- resblock loop (no barriers, no act LDS) ----
    #pragma unroll 1
    for (int i = 0; i < NB_; ++i) {
        // broadcast bias/tp fragments (D layout: f = 16T + 4q + r)
        floatx4 tpv[4], bb0[4], bb1[4];
        #pragma unroll
        for (int T = 0; T < 4; ++T) {
            int off = i * 64 + (T << 4) + (q << 2);
            tpv[T] = *(const floatx4*)(tp_l + off);
            bb0[T] = *(const floatx4*)(b0_l + off);
            bb1[T] = *(const floatx4*)(b1_l + off);
        }
        // --- conditioning: net += c @ Wc + tp ---
        {
            const _Float16* wbase = ws_w + ((size_t)(0 * 5 + i) * 512) * 8;
            half8 A[4][2];
            #pragma unroll
            for (int T = 0; T < 4; ++T)
                #pragma unroll
                for (int h = 0; h < 2; ++h)
                    A[T][h] = ldg8(wbase + ((T * 128 + h * 64 + q * 16 + m15) * 8));
            #pragma unroll
            for (int t = 0; t < TILES_; ++t) {
                if (!act[t]) continue;
                #pragma unroll
                for (int T = 0; T < 4; ++T) {
                    floatx4 a = net4[t][T];
                    a = __builtin_amdgcn_mfma_f32_16x16x32_f16(A[T][0], cB[t][0], a, 0, 0, 0);
                    a = __builtin_amdgcn_mfma_f32_16x16x32_f16(A[T][1], cB[t][1], a, 0, 0, 0);
                    net4[t][T] = a + tpv[T];
                }
            }
        }
        // --- blk0 + blk1 fused per tile: net += relu(relu(net)@W0+b0)@W1 + b1 ---
        {
            const _Float16* w0 = ws_w + ((size_t)(1 * 5 + i) * 512) * 8;
            const _Float16* w1 = ws_w + ((size_t)(2 * 5 + i) * 512) * 8;
            half8 A0[4][2], A1[4][2];
            #pragma unroll
            for (int T = 0; T < 4; ++T)
                #pragma unroll
                for (int h = 0; h < 2; ++h) {
                    int off = (T * 128 + h * 64 + q * 16 + m15) * 8;
                    A0[T][h] = ldg8(w0 + off);
                    A1[T][h] = ldg8(w1 + off);
                }
            #pragma unroll
            for (int t = 0; t < TILES_; ++t) {
                if (!act[t]) continue;
                half8 Bn0 = packB(net4[t][0], net4[t][1]);
                half8 Bn1 = packB(net4[t][2], net4[t][3]);
                floatx4 hh[4];
                #pragma unroll
                for (int T = 0; T < 4; ++T) {
                    floatx4 a = bb0[T];
                    a = __builtin_amdgcn_mfma_f32_16x16x32_f16(A0[T][0], Bn0, a, 0, 0, 0);
                    a = __builtin_amdgcn_mfma_f32_16x16x32_f16(A0[T][1], Bn1, a, 0, 0, 0);
                    hh[T] = a;
                }
                half8 Bh0 = packB(hh[0], hh[1]);
                half8 Bh1 = packB(hh[2], hh[3]);
                #pragma unroll
                for (int T = 0; T < 4; ++T) {
                    floatx4 a = bb1[T];
                    a = __builtin_amdgcn_mfma_f32_16x16x32_f16(A1[T][0], Bh0, a, 0, 0, 0);
                    a = __builtin_amdgcn_mfma_f32_16x16x32_f16(A1[T][1], Bh1, a, 0, 0, 0);
                    net4[t][T] += a;
                }
            }
        }
    }

    // ---- output: out = relu(net) @ fc_out + b ----
    half8 Ao0 = ldg8(ws_fco + (0 * 64 + q * 16 + m15) * 8);
    half8 Ao1 = ldg8(ws_fco + (1 * 64 + q * 16 + m15) * 8);
    floatx4 ob;
    #pragma unroll
    for (int r = 0; r < 4; ++r) ob[r] = fob_l[(q << 2) + r];
    #pragma unroll
    for (int t = 0; t < TILES_; ++t) {
        if (!act[t]) continue;
        half8 Bn0 = packB(net4[t][0], net4[t][1]);
        half8 Bn1 = packB(net4[t][2], net4[t][3]);
        floatx4 a = ob;
        a = __builtin_amdgcn_mfma_f32_16x16x32_f16(Ao0, Bn0, a, 0, 0, 0);
        a = __builtin_amdgcn_mfma_f32_16x16x32_f16(Ao1, Bn1, a, 0, 0, 0);
        if (q < 3) {  // out rows 12..15 are padding
            long g = gbase + tileid[t] * 16 + m15;
            *(float4*)(out_g + g * OUT_ + (q << 2)) = make_float4(a[0], a[1], a[2], a[3]);
        }
    }
}

// ---------------------------------------------------------------------------
extern "C" void kernel_launch(void* const* d_in, const int* in_sizes, int n_in,
                              void* d_out, int out_size, void* d_ws, size_t ws_size,
                              hipStream_t stream) {
    const float* p        = (const float*)d_in[0];
    const float* c        = (const float*)d_in[1];
    const float* tf       = (const float*)d_in[2];
    const float* fc_p_W   = (const float*)d_in[3];
    const float* fc_p_b   = (const float*)d_in[4];
    const float* fc_c_W   = (const float*)d_in[5];
    const float* fc_c_b   = (const float*)d_in[6];
    const float* blk0_W   = (const float*)d_in[7];
    const float* blk0_b   = (const float*)d_in[8];
    const float* blk1_W   = (const float*)d_in[9];
    const float* blk1_b   = (const float*)d_in[10];
    const float* fc_out_W = (const float*)d_in[11];
    const float* fc_out_b = (const float*)d_in[12];
    float* out = (float*)d_out;

    // ws: ws_w 7680*16B = 122880 B | ws_fco 128*16B = 2048 B | ws_tp 8*5*64 f32 = 10240 B
    _Float16* ws_w   = (_Float16*)d_ws;
    _Float16* ws_fco = ws_w + 7680 * 8;
    float*    ws_tp  = (float*)(ws_fco + 128 * 8);

    prep_weights<<<31, THREADS, 0, stream>>>(fc_c_W, blk0_W, blk1_W, fc_out_W, ws_w, ws_fco);
    task_proj_kernel<<<B_ * NB_, THREADS, 0, stream>>>(tf, fc_c_W, fc_c_b, fc_p_b, ws_tp);
    decoder_kernel<<<B_ * BLOCKS_PER_BATCH, THREADS, 0, stream>>>(
        p, c, blk0_b, blk1_b, fc_p_W, fc_out_b, ws_w, ws_fco, ws_tp, out);
}

// Round 4
// 237.264 us; speedup vs baseline: 7.2326x; 1.0440x over previous
//
#include <hip/hip_runtime.h>

// AblationDecoder: B=8, N=50000, DIM=3, C_DIM=64, TASK_DIM=512, H=64, NB=5, OUT=12
// R4: R3's register-resident chain + (1) weight replication x8 to kill L2 hot-line
// contention, (2) explicit 2-buffer stage prefetch pipeline, (3) 64-thread blocks
// with zero LDS / zero barriers, (4) parallel fused pre-kernels.
#define B_    8
#define N_    50000
#define NB_   5
#define OUT_  12
#define TILES_ 4
#define TILES_PER_BATCH 3125              // 50000/16
#define BLOCKS_PER_BATCH 782              // ceil(3125/4)

typedef _Float16 half8 __attribute__((ext_vector_type(8)));
typedef float   floatx4 __attribute__((ext_vector_type(4)));

__device__ __forceinline__ half8 ldg8(const _Float16* p) {
    union { uint4 u; half8 h; } x;
    x.u = *(const uint4*)p;
    return x.h;
}

// B fragment from two D-layout accumulators (relu + f32->f16), pure registers.
__device__ __forceinline__ half8 packB(floatx4 a, floatx4 b) {
    half8 r;
    r[0] = (_Float16)fmaxf(a[0], 0.f); r[1] = (_Float16)fmaxf(a[1], 0.f);
    r[2] = (_Float16)fmaxf(a[2], 0.f); r[3] = (_Float16)fmaxf(a[3], 0.f);
    r[4] = (_Float16)fmaxf(b[0], 0.f); r[5] = (_Float16)fmaxf(b[1], 0.f);
    r[6] = (_Float16)fmaxf(b[2], 0.f); r[7] = (_Float16)fmaxf(b[3], 0.f);
    return r;
}

// load one stage's 8 A-fragments (frag j = A[T*2+h])
__device__ __forceinline__ void load8(half8 (&A)[8], const _Float16* base, int q16m) {
    #pragma unroll
    for (int T = 0; T < 4; ++T)
        #pragma unroll
        for (int h = 0; h < 2; ++h)
            A[T * 2 + h] = ldg8(base + (size_t)(T * 128 + h * 64 + q16m) * 8);
}

// ---------------------------------------------------------------------------
// Pre-kernel A (fused): blocks 0..31 build f16 A-fragment weights (R replicas);
// blocks 32..111 compute task-feature partial projections (8 chunks per (b,i)).
// ws_w layout per replica: chunk ((mat*5+i)*4+T)*128 + h*64 + q*16 + m15, 8 halves:
//   mat==0 (Wc):   j -> feature k = 32h+8q+j          (natural-k c path)
//   mat==1/2:      j -> feature f = 32h+16*(j>>2)+4q+(j&3)  (register D->B path)
// ws_fco per replica: 512 chunks, chunks 0..127 = fc_out (sigma'd), rest zero.
// ---------------------------------------------------------------------------
__global__ void prep_kernel(const float* __restrict__ fc_c_W,
                            const float* __restrict__ blk0_W,
                            const float* __restrict__ blk1_W,
                            const float* __restrict__ fc_out_W,
                            const float* __restrict__ tf,
                            _Float16* __restrict__ ws_w,
                            _Float16* __restrict__ ws_fco,
                            float* __restrict__ partials, int R) {
    int bid = blockIdx.x, tid = threadIdx.x;
    if (bid < 32) {
        int u = bid * 256 + tid;          // 0..8191
        if (u < 7680) {
            int m15 = u & 15, q = (u >> 4) & 3, h = (u >> 6) & 1, T = (u >> 7) & 3;
            int mi = u >> 9;              // 0..14
            int mat = mi / 5, i = mi % 5;
            int n = T * 16 + m15;
            _Float16 out[8];
            #pragma unroll
            for (int j = 0; j < 8; ++j) {
                float v;
                if (mat == 0) {
                    int k = 32 * h + 8 * q + j;
                    v = fc_c_W[((size_t)i * 576 + k) * 64 + n];
                } else {
                    int f = 32 * h + 16 * (j >> 2) + 4 * q + (j & 3);
                    const float* W = (mat == 1) ? blk0_W : blk1_W;
                    v = W[((size_t)i * 64 + f) * 64 + n];
                }
                out[j] = (_Float16)v;
            }
            uint4 val = *(uint4*)out;
            for (int r = 0; r < R; ++r)
                *(uint4*)(ws_w + (size_t)r * 61440 + (size_t)u * 8) = val;
        } else {
            int e = u - 7680;             // 0..511
            _Float16 out[8] = {};
            if (e < 128) {
                int m15 = e & 15, q = (e >> 4) & 3, h = (e >> 6) & 1;
                #pragma unroll
                for (int j = 0; j < 8; ++j) {
                    int f = 32 * h + 16 * (j >> 2) + 4 * q + (j & 3);
                    out[j] = (m15 < OUT_) ? (_Float16)fc_out_W[f * OUT_ + m15] : (_Float16)0.f;
                }
            }
            uint4 val = *(uint4*)out;
            for (int r = 0; r < R; ++r)
                *(uint4*)(ws_fco + (size_t)r * 4096 + (size_t)e * 8) = val;
        }
    } else {
        // task partials: idx2 -> (b, i, half); 4 groups of 64 t's each
        int idx2 = bid - 32;              // 0..79
        int b = idx2 / 10, rem = idx2 % 10, i = rem >> 1, hf = rem & 1;
        int g = tid >> 6, j = tid & 63;
        const float* W  = fc_c_W + ((size_t)i * 576 + 64) * 64;
        const float* tb = tf + b * 512;
        int t0 = hf * 256 + g * 64;
        float acc = 0.f;
        #pragma unroll 8
        for (int t = 0; t < 64; ++t)
            acc += tb[t0 + t] * W[(size_t)(t0 + t) * 64 + j];
        partials[(((b * 5 + i) << 3) + (hf * 4 + g)) * 64 + j] = acc;
    }
}

// Pre-kernel B: tp[b][i][j] = sum_8 partials + fc_c_b + (i==0 ? fc_p_b : 0)
__global__ void finalize_tp(const float* __restrict__ partials,
                            const float* __restrict__ fc_c_b,
                            const float* __restrict__ fc_p_b,
                            float* __restrict__ tp) {
    int u = blockIdx.x * 256 + threadIdx.x;
    if (u >= 2560) return;
    int b = u / 320, rem = u % 320, i = rem >> 6, j = rem & 63;
    float s = fc_c_b[i * 64 + j] + ((i == 0) ? fc_p_b[j] : 0.f);
    #pragma unroll
    for (int k = 0; k < 8; ++k)
        s += partials[(((b * 5 + i) << 3) + k) * 64 + j];
    tp[u] = s;
}

// ---------------------------------------------------------------------------
// One resblock: cond (Ac) -> [issue blk1 into Ac] -> blk0 (Ab) + blk1 (Ac) fused
// per tile -> [issue next cond/fco into Ab] -> [issue next blk0 into Ac].
// Caller alternates (X,Y)/(Y,X) so every compute reads a buffer whose loads were
// issued one stage earlier.
// ---------------------------------------------------------------------------
__device__ __forceinline__ void resblock(
    half8 (&Ac)[8], half8 (&Ab)[8],
    floatx4 (&net4)[TILES_][4], const half8 (&cB)[TILES_][2],
    int tc, int i, int q, int q16m,
    const float* __restrict__ tp_b, const float* __restrict__ b0g,
    const float* __restrict__ b1g, const _Float16* __restrict__ wsr,
    const _Float16* __restrict__ next_cond_base, bool last)
{
    floatx4 tpv[4], bb0[4], bb1[4];
    #pragma unroll
    for (int T = 0; T < 4; ++T) {
        int off = i * 64 + 16 * T + 4 * q;
        tpv[T] = *(const floatx4*)(tp_b + off);
        bb0[T] = *(const floatx4*)(b0g + off);
        bb1[T] = *(const floatx4*)(b1g + off);
    }
    // ---- conditioning: net += c @ Wc + tp ----
    #pragma unroll
    for (int t = 0; t < TILES_; ++t) {
        if (t >= tc) break;
        #pragma unroll
        for (int T = 0; T < 4; ++T) {
            floatx4 a = net4[t][T];
            a = __builtin_amdgcn_mfma_f32_16x16x32_f16(Ac[2 * T], cB[t][0], a, 0, 0, 0);
            a = __builtin_amdgcn_mfma_f32_16x16x32_f16(Ac[2 * T + 1], cB[t][1], a, 0, 0, 0);
            net4[t][T] = a + tpv[T];
        }
    }
    load8(Ac, wsr + (size_t)(10 + i) * 4096, q16m);      // prefetch blk1_i
    // ---- blk0+blk1 fused per tile ----
    #pragma unroll
    for (int t = 0; t < TILES_; ++t) {
        if (t >= tc) break;
        half8 Bn0 = packB(net4[t][0], net4[t][1]);
        half8 Bn1 = packB(net4[t][2], net4[t][3]);
        floatx4 hh[4];
        #pragma unroll
        for (int T = 0; T < 4; ++T) {
            floatx4 a = bb0[T];
            a = __builtin_amdgcn_mfma_f32_16x16x32_f16(Ab[2 * T], Bn0, a, 0, 0, 0);
            a = __builtin_amdgcn_mfma_f32_16x16x32_f16(Ab[2 * T + 1], Bn1, a, 0, 0, 0);
            hh[T] = a;
        }
        half8 Bh0 = packB(hh[0], hh[1]);
        half8 Bh1 = packB(hh[2], hh[3]);
        #pragma unroll
        for (int T = 0; T < 4; ++T) {
            floatx4 a = bb1[T];
            a = __builtin_amdgcn_mfma_f32_16x16x32_f16(Ac[2 * T], Bh0, a, 0, 0, 0);
            a = __builtin_amdgcn_mfma_f32_16x16x32_f16(Ac[2 * T + 1], Bh1, a, 0, 0, 0);
            net4[t][T] += a;
        }
    }
    load8(Ab, next_cond_base, q16m);                     // prefetch cond_{i+1} / fco
    if (!last)
        load8(Ac, wsr + (size_t)(5 + i + 1) * 4096, q16m);  // prefetch blk0_{i+1}
}

// ---------------------------------------------------------------------------
// Main decoder: 64-thread blocks (1 wave), 4 contiguous 16-pt tiles per wave.
// No LDS, no barriers. Weight replica = blockIdx & rmask.
// ---------------------------------------------------------------------------
__global__ __launch_bounds__(64, 2) void decoder_kernel(
    const float* __restrict__ p_g, const float* __restrict__ c_g,
    const float* __restrict__ blk0_b, const float* __restrict__ blk1_b,
    const float* __restrict__ fc_p_W, const float* __restrict__ fc_out_b,
    const _Float16* __restrict__ ws_w, const _Float16* __restrict__ ws_fco,
    const float* __restrict__ tp_g, float* __restrict__ out_g, int rmask)
{
    const int bid   = blockIdx.x;
    const int batch = bid / BLOCKS_PER_BATCH;
    const int blk   = bid % BLOCKS_PER_BATCH;
    const int tile0 = blk * TILES_;
    const int tc    = min(TILES_, TILES_PER_BATCH - tile0);
    const long gbase = (long)batch * N_ + (long)tile0 * 16;
    const int lane = threadIdx.x;
    const int q = lane >> 4, m15 = lane & 15;
    const int q16m = q * 16 + m15;
    const _Float16* wsr  = ws_w  + (size_t)(bid & rmask) * 61440;
    const _Float16* fcor = ws_fco + (size_t)(bid & rmask) * 4096;
    const float* tp_b = tp_g + batch * (NB_ * 64);

    half8 X[8], Y[8];
    load8(X, wsr, q16m);                     // cond_0
    load8(Y, wsr + (size_t)5 * 4096, q16m);  // blk0_0

    // ---- c -> B-operand registers (held for all 5 resblocks) ----
    half8 cB[TILES_][2];
    #pragma unroll
    for (int t = 0; t < TILES_; ++t) {
        if (t >= tc) break;
        const float* cr = c_g + (size_t)(gbase + t * 16 + m15) * 64;
        #pragma unroll
        for (int h = 0; h < 2; ++h) {
            float4 v0 = *(const float4*)(cr + 32 * h + 8 * q);
            float4 v1 = *(const float4*)(cr + 32 * h + 8 * q + 4);
            half8 r;
            r[0] = (_Float16)v0.x; r[1] = (_Float16)v0.y;
            r[2] = (_Float16)v0.z; r[3] = (_Float16)v0.w;
            r[4] = (_Float16)v1.x; r[5] = (_Float16)v1.y;
            r[6] = (_Float16)v1.z; r[7] = (_Float16)v1.w;
            cB[t][h] = r;
        }
    }

    // ---- net init: p @ fc_p_W (biases folded into tp[0]) ----
    floatx4 fw[3][4];
    #pragma unroll
    for (int d = 0; d < 3; ++d)
        #pragma unroll
        for (int T = 0; T < 4; ++T)
            fw[d][T] = *(const floatx4*)(fc_p_W + d * 64 + 16 * T + 4 * q);
    floatx4 net4[TILES_][4];
    #pragma unroll
    for (int t = 0; t < TILES_; ++t) {
        if (t >= tc) break;
        long g = gbase + t * 16 + m15;
        float pp0 = p_g[g * 3 + 0], pp1 = p_g[g * 3 + 1], pp2 = p_g[g * 3 + 2];
        #pragma unroll
        for (int T = 0; T < 4; ++T)
            net4[t][T] = fw[0][T] * pp0 + fw[1][T] * pp1 + fw[2][T] * pp2;
    }

    // ---- 5 resblocks, alternating prefetch buffers ----
    resblock(X, Y, net4, cB, tc, 0, q, q16m, tp_b, blk0_b, blk1_b, wsr, wsr + (size_t)1 * 4096, false);
    resblock(Y, X, net4, cB, tc, 1, q, q16m, tp_b, blk0_b, blk1_b, wsr, wsr + (size_t)2 * 4096, false);
    resblock(X, Y, net4, cB, tc, 2, q, q16m, tp_b, blk0_b, blk1_b, wsr, wsr + (size_t)3 * 4096, false);
    resblock(Y, X, net4, cB, tc, 3, q, q16m, tp_b, blk0_b, blk1_b, wsr, wsr + (size_t)4 * 4096, false);
    resblock(X, Y, net4, cB, tc, 4, q, q16m, tp_b, blk0_b, blk1_b, wsr, fcor, true);

    // ---- output: out = relu(net) @ fc_out + b  (fco frags now in Y[0],Y[1]) ----
    floatx4 ob = {0.f, 0.f, 0.f, 0.f};
    if (q < 3) ob = *(const floatx4*)(fc_out_b + 4 * q);
    #pragma unroll
    for (int t = 0; t < TILES_; ++t) {
        if (t >= tc) break;
        half8 Bn0 = packB(net4[t][0], net4[t][1]);
        half8 Bn1 = packB(net4[t][2], net4[t][3]);
        floatx4 a = ob;
        a = __builtin_amdgcn_mfma_f32_16x16x32_f16(Y[0], Bn0, a, 0, 0, 0);
        a = __builtin_amdgcn_mfma_f32_16x16x32_f16(Y[1], Bn1, a, 0, 0, 0);
        if (q < 3) {
            long g = gbase + t * 16 + m15;
            *(float4*)(out_g + g * OUT_ + 4 * q) = make_float4(a[0], a[1], a[2], a[3]);
        }
    }
}

// ---------------------------------------------------------------------------
extern "C" void kernel_launch(void* const* d_in, const int* in_sizes, int n_in,
                              void* d_out, int out_size, void* d_ws, size_t ws_size,
                              hipStream_t stream) {
    const float* p        = (const float*)d_in[0];
    const float* c        = (const float*)d_in[1];
    const float* tf       = (const float*)d_in[2];
    const float* fc_p_W   = (const float*)d_in[3];
    const float* fc_p_b   = (const float*)d_in[4];
    const float* fc_c_W   = (const float*)d_in[5];
    const float* fc_c_b   = (const float*)d_in[6];
    const float* blk0_W   = (const float*)d_in[7];
    const float* blk0_b   = (const float*)d_in[8];
    const float* blk1_W   = (const float*)d_in[9];
    const float* blk1_b   = (const float*)d_in[10];
    const float* fc_out_W = (const float*)d_in[11];
    const float* fc_out_b = (const float*)d_in[12];
    float* out = (float*)d_out;

    // pick replica count that fits ws: R*(61440+4096)*2B + partials 81920B + tp 10240B
    int R = 8;
    while (R > 1 && ((size_t)R * (61440 + 4096) * 2 + 81920 + 10240) > ws_size) R >>= 1;

    _Float16* ws_w   = (_Float16*)d_ws;
    _Float16* ws_fco = ws_w + (size_t)R * 61440;
    float* partials  = (float*)(ws_fco + (size_t)R * 4096);
    float* tp        = partials + 20480;

    prep_kernel<<<112, 256, 0, stream>>>(fc_c_W, blk0_W, blk1_W, fc_out_W, tf,
                                         ws_w, ws_fco, partials, R);
    finalize_tp<<<10, 256, 0, stream>>>(partials, fc_c_b, fc_p_b, tp);
    decoder_kernel<<<B_ * BLOCKS_PER_BATCH, 64, 0, stream>>>(
        p, c, blk0_b, blk1_b, fc_p_W, fc_out_b, ws_w, ws_fco, tp, out, R - 1);
}